// Round 3
// baseline (159.936 us; speedup 1.0000x reference)
//
#include <hip/hip_runtime.h>

#define EXTENT 7
#define CHANNELS 256
#define NPTS (EXTENT * EXTENT)  // 49

typedef float v4f __attribute__((ext_vector_type(4)));

// ---------------------------------------------------------------------------
// R4 (resubmit; R2 bench was a container-infra failure, not a kernel verdict):
// prefetch-to-LLC prime pass.
// Evidence: main kernel is pinned at 3.4 TB/s (54% of achievable) regardless
// of per-wave MLP (R0: VGPR=20, R1: VGPR=52 -> identical dur). FETCH_SIZE
// (93.5 MB) == p2+p3 footprint, i.e. each 64B line is fetched exactly once
// but in box order = random line order over 67 MB -> DRAM activate-bound,
// ~50% HBM efficiency (6.3 * 0.5 = 3.2 ~= measured 3.4 TB/s). The harness's
// 262 MB fills evict L3 between iterations, so these are true HBM reads.
// Fix: read p2+p3 once in streaming order (grid-stride v4f, the same pattern
// fillBuffer uses to hit 6.3 TB/s) so they land in the 256 MB memory-side
// Infinity Cache; the main kernel's random misses then hit L3 instead of HBM.
// ---------------------------------------------------------------------------
__global__ __launch_bounds__(256) void prime_llc_kernel(
    const float* __restrict__ p2,
    const float* __restrict__ p3)
{
    // p2: 256*256*256 floats = 4,194,304 v4f; p3: 128*128*256 = 1,048,576 v4f.
    const size_t n2 = (size_t)256 * 256 * 256 / 4;
    const size_t n3 = (size_t)128 * 128 * 256 / 4;
    const size_t idx    = (size_t)blockIdx.x * blockDim.x + threadIdx.x;
    const size_t stride = (size_t)gridDim.x * blockDim.x;  // 524288 -> 8 + 2 iters

    v4f acc = {0.f, 0.f, 0.f, 0.f};
    for (size_t i = idx; i < n2; i += stride)
        acc += ((const v4f*)p2)[i];
    for (size_t i = idx; i < n3; i += stride)
        acc += ((const v4f*)p3)[i];
    // Keep the loads live without any store (guide rule #17).
    float keep = acc.x + acc.y + acc.z + acc.w;
    asm volatile("" :: "v"(keep));
}

// Grid = 4 * n_boxes. blockIdx = q*n_boxes + box. 256 threads:
// (tid & 63) -> 4 channels via v4f (64 lanes x 16B = full 1KB channel row,
// coalesced); sub = q*4 + (tid>>6) in [0,16) -> 3 grid points per wave
// (+ point 48 on sub==0, wave-uniform branch). Explicit 3-stage pipeline
// (addresses -> all 12 loads -> blends/stores) keeps 12 KB/wave in flight.
__global__ __launch_bounds__(256) void roi_align_pyramid_kernel(
    const float* __restrict__ metadata,
    const float* __restrict__ boxes,
    const float* __restrict__ p2,
    const float* __restrict__ p3,
    const float* __restrict__ p4,
    const float* __restrict__ p5,
    float* __restrict__ out,
    int n_boxes)
{
    const int box = blockIdx.x % n_boxes;
    const int q   = blockIdx.x / n_boxes;      // 0..3
    const int tid = threadIdx.x;
    const int sub = (q << 2) | (tid >> 6);     // 0..15, uniform per wave
    const int c   = (tid & 63) << 2;           // channel offset

    const float rows = metadata[0];
    const float cols = metadata[1];

    const float x1 = boxes[box * 4 + 0];
    const float y1 = boxes[box * 4 + 1];
    const float x2 = boxes[box * 4 + 2];
    const float y2 = boxes[box * 4 + 3];

    // Level selection — replicate reference fp32 math.
    const float h = y2 - y1;
    const float w = x2 - x1;
    float roi_level = logf(sqrtf(h * w) / sqrtf(rows * cols)) / logf(2.0f);
    roi_level = fminf(5.0f, fmaxf(2.0f, 4.0f + rintf(roi_level)));
    const int lvl = (int)roi_level;  // 2..5

    const float* feat;
    int H;
    if      (lvl == 2) { feat = p2; H = 256; }
    else if (lvl == 3) { feat = p3; H = 128; }
    else if (lvl == 4) { feat = p4; H = 64; }
    else               { feat = p5; H = 32; }
    const int W = H;
    const size_t rowstr = (size_t)W * CHANNELS;

    // Normalized box coords (tf.crop_and_resize convention).
    const float ny1 = y1 / (rows - 1.0f);
    const float ny2 = y2 / (rows - 1.0f);
    const float nx1 = x1 / (cols - 1.0f);
    const float nx2 = x2 / (cols - 1.0f);

    float* outp = out + (size_t)box * NPTS * CHANNELS + c;

    // Stage 0: addresses + weights for a point.
    auto setup = [&](int p, const float*& base,
                     float& w00, float& w01, float& w10, float& w11) {
        const int gy = p / EXTENT;
        const int gx = p - gy * EXTENT;

        const float gyf = (float)gy / (float)(EXTENT - 1);
        const float ysv = (ny1 + (ny2 - ny1) * gyf) * (float)(H - 1);
        float y0f = floorf(ysv);
        y0f = fminf(fmaxf(y0f, 0.0f), (float)(H - 2));
        const int   y0 = (int)y0f;
        const float wy = ysv - y0f;

        const float gxf = (float)gx / (float)(EXTENT - 1);
        const float xsv = (nx1 + (nx2 - nx1) * gxf) * (float)(W - 1);
        float x0f = floorf(xsv);
        x0f = fminf(fmaxf(x0f, 0.0f), (float)(W - 2));
        const int   x0 = (int)x0f;
        const float wx = xsv - x0f;

        base = feat + ((size_t)(y0 * W + x0)) * CHANNELS + c;
        w00 = (1.0f - wy) * (1.0f - wx);
        w01 = (1.0f - wy) * wx;
        w10 = wy * (1.0f - wx);
        w11 = wy * wx;
    };

    const float* base[3];
    float w00[3], w01[3], w10[3], w11[3];
    #pragma unroll
    for (int k = 0; k < 3; ++k)
        setup(sub + 16 * k, base[k], w00[k], w01[k], w10[k], w11[k]);

    // Stage 1: issue ALL loads before any use (static indices -> registers).
    v4f f00[3], f01[3], f10[3], f11[3];
    #pragma unroll
    for (int k = 0; k < 3; ++k) {
        f00[k] = *(const v4f*)(base[k]);
        f01[k] = *(const v4f*)(base[k] + CHANNELS);
        f10[k] = *(const v4f*)(base[k] + rowstr);
        f11[k] = *(const v4f*)(base[k] + rowstr + CHANNELS);
    }

    // Tail point 48 (sub==0 only; sub is wave-uniform so no divergence).
    const bool tail = (sub == 0);
    const float* tb = base[0];
    float t00 = 0.f, t01 = 0.f, t10 = 0.f, t11 = 0.f;
    v4f g00 = {}, g01 = {}, g10 = {}, g11 = {};
    if (tail) {
        setup(48, tb, t00, t01, t10, t11);
        g00 = *(const v4f*)(tb);
        g01 = *(const v4f*)(tb + CHANNELS);
        g10 = *(const v4f*)(tb + rowstr);
        g11 = *(const v4f*)(tb + rowstr + CHANNELS);
    }

    // Stage 2: blend + store (write-once data: nontemporal keeps feature
    // lines resident in L2/L3).
    #pragma unroll
    for (int k = 0; k < 3; ++k) {
        v4f r = f00[k] * w00[k] + f01[k] * w01[k]
              + f10[k] * w10[k] + f11[k] * w11[k];
        __builtin_nontemporal_store(r, (v4f*)(outp + (size_t)(sub + 16 * k) * CHANNELS));
    }
    if (tail) {
        v4f r = g00 * t00 + g01 * t01 + g10 * t10 + g11 * t11;
        __builtin_nontemporal_store(r, (v4f*)(outp + (size_t)48 * CHANNELS));
    }
}

extern "C" void kernel_launch(void* const* d_in, const int* in_sizes, int n_in,
                              void* d_out, int out_size, void* d_ws, size_t ws_size,
                              hipStream_t stream) {
    const float* metadata = (const float*)d_in[0];
    const float* boxes    = (const float*)d_in[1];
    const float* p2       = (const float*)d_in[2];
    const float* p3       = (const float*)d_in[3];
    const float* p4       = (const float*)d_in[4];
    const float* p5       = (const float*)d_in[5];
    float* out = (float*)d_out;

    const int n_boxes = in_sizes[1] / 4;  // 1024

    // Pass 1: pull p2+p3 (84 MB, 99.9% of read traffic — the box-size
    // distribution never selects levels 4/5) into the Infinity Cache in
    // streaming order. 2048 blocks -> 524288 threads -> 8+2 v4f iters each.
    prime_llc_kernel<<<dim3(2048), dim3(256), 0, stream>>>(p2, p3);

    // Pass 2: the RoI-align itself; random reads now hit L3 instead of HBM.
    roi_align_pyramid_kernel<<<dim3(n_boxes * 4), dim3(256), 0, stream>>>(
        metadata, boxes, p2, p3, p4, p5, out, n_boxes);
}

// Round 4
// 144.689 us; speedup vs baseline: 1.1054x; 1.1054x over previous
//
#include <hip/hip_runtime.h>

#define EXTENT 7
#define CHANNELS 256
#define NPTS (EXTENT * EXTENT)  // 49

typedef float v4f __attribute__((ext_vector_type(4)));

// ---------------------------------------------------------------------------
// R5: sorted moving-window execution.
// Evidence trail: per-wave MLP x3 (R1), occupancy 61%->33% (R0 vs R1), and
// LLC priming (R3) ALL left the main kernel at 3.4 TB/s / 43 us. With 4096
// blocks all ~resident at once, the memory controllers see random 2KB chunks
// spanning all of p2 (67 MB) at every instant -> zero DRAM row locality.
// FETCH (93 MB) ~= footprint, so bytes are compulsory; only ordering is left.
// Fix: (1) bucket-sort boxes by (level, y-center) — p2 is row-major, so a
// y-band is contiguous memory; (2) 512 persistent blocks grid-stride the
// 4096 (box,q) items in sorted order -> instantaneous read window is a
// ~18 MB contiguous slab (128 y-adjacent boxes) instead of 67 MB scattered.
// Writes stay contiguous per box (49 KB chunks), unaffected by box order.
// ---------------------------------------------------------------------------

// Single-block bucket sort: key = (level-2)<<8 | y_bucket(256 bands).
// LDS histogram + Hillis-Steele scan + scatter. n_boxes <= 1024 (harness: 1024).
__global__ __launch_bounds__(1024) void sort_boxes_kernel(
    const float* __restrict__ metadata,
    const float* __restrict__ boxes,
    int* __restrict__ sorted,
    int n_boxes)
{
    __shared__ unsigned cnt[1024];
    __shared__ unsigned scanA[1024];
    __shared__ unsigned scanB[1024];
    const int tid = threadIdx.x;
    cnt[tid] = 0;
    __syncthreads();

    const float rows = metadata[0];
    const float cols = metadata[1];

    int key = 0;
    if (tid < n_boxes) {
        const float x1 = boxes[tid * 4 + 0];
        const float y1 = boxes[tid * 4 + 1];
        const float x2 = boxes[tid * 4 + 2];
        const float y2 = boxes[tid * 4 + 3];
        const float h = y2 - y1;
        const float w = x2 - x1;
        float rl = logf(sqrtf(h * w) / sqrtf(rows * cols)) / logf(2.0f);
        rl = fminf(5.0f, fmaxf(2.0f, 4.0f + rintf(rl)));
        const int lvl = (int)rl;                      // 2..5
        const float cy = 0.5f * (y1 + y2);
        int yb = (int)(cy * (256.0f / rows));
        yb = min(max(yb, 0), 255);
        key = ((lvl - 2) << 8) | yb;                  // 0..1023
        atomicAdd(&cnt[key], 1u);
    }
    __syncthreads();

    // Inclusive scan over the 1024 buckets (10 Hillis-Steele steps).
    scanA[tid] = cnt[tid];
    __syncthreads();
    unsigned* src = scanA;
    unsigned* dst = scanB;
    for (int d = 1; d < 1024; d <<= 1) {
        unsigned v = src[tid];
        if (tid >= d) v += src[tid - d];
        dst[tid] = v;
        __syncthreads();
        unsigned* t = src; src = dst; dst = t;
    }

    // Scatter: pos = inclusive[key] - (remaining count). atomicSub returns the
    // old value in [1..cnt0], giving distinct pos in [exclusive, inclusive).
    if (tid < n_boxes) {
        const unsigned old = atomicSub(&cnt[key], 1u);
        const unsigned pos = src[key] - old;
        sorted[pos] = tid;
    }
}

// 512 persistent blocks x 256 threads. Grid-stride over items = 4*n_boxes:
// at "iteration j" the resident blocks process items [j*512,(j+1)*512) =
// 128 consecutive sorted boxes x 4 quadrants. Per item: (tid&63) -> 4
// channels via v4f (64 lanes x 16B = full 1KB channel row, coalesced);
// sub = q*4 + (tid>>6) in [0,16) -> 3 grid points (+ point 48 on sub==0,
// wave-uniform). Explicit pipeline: addresses -> all 12 loads -> blends.
__global__ __launch_bounds__(256) void roi_align_pyramid_kernel(
    const float* __restrict__ metadata,
    const float* __restrict__ boxes,
    const float* __restrict__ p2,
    const float* __restrict__ p3,
    const float* __restrict__ p4,
    const float* __restrict__ p5,
    const int* __restrict__ sorted,
    float* __restrict__ out,
    int n_boxes)
{
    const int tid = threadIdx.x;
    const int c   = (tid & 63) << 2;           // channel offset
    const float rows = metadata[0];
    const float cols = metadata[1];
    const int items = n_boxes * 4;

    for (int idx = blockIdx.x; idx < items; idx += gridDim.x) {
        const int box = sorted[idx >> 2];
        const int q   = idx & 3;               // 0..3
        const int sub = (q << 2) | (tid >> 6); // 0..15, uniform per wave

        const float x1 = boxes[box * 4 + 0];
        const float y1 = boxes[box * 4 + 1];
        const float x2 = boxes[box * 4 + 2];
        const float y2 = boxes[box * 4 + 3];

        // Level selection — replicate reference fp32 math.
        const float h = y2 - y1;
        const float w = x2 - x1;
        float roi_level = logf(sqrtf(h * w) / sqrtf(rows * cols)) / logf(2.0f);
        roi_level = fminf(5.0f, fmaxf(2.0f, 4.0f + rintf(roi_level)));
        const int lvl = (int)roi_level;  // 2..5

        const float* feat;
        int H;
        if      (lvl == 2) { feat = p2; H = 256; }
        else if (lvl == 3) { feat = p3; H = 128; }
        else if (lvl == 4) { feat = p4; H = 64; }
        else               { feat = p5; H = 32; }
        const int W = H;
        const size_t rowstr = (size_t)W * CHANNELS;

        const float ny1 = y1 / (rows - 1.0f);
        const float ny2 = y2 / (rows - 1.0f);
        const float nx1 = x1 / (cols - 1.0f);
        const float nx2 = x2 / (cols - 1.0f);

        float* outp = out + (size_t)box * NPTS * CHANNELS + c;

        auto setup = [&](int p, const float*& base,
                         float& w00, float& w01, float& w10, float& w11) {
            const int gy = p / EXTENT;
            const int gx = p - gy * EXTENT;

            const float gyf = (float)gy / (float)(EXTENT - 1);
            const float ysv = (ny1 + (ny2 - ny1) * gyf) * (float)(H - 1);
            float y0f = floorf(ysv);
            y0f = fminf(fmaxf(y0f, 0.0f), (float)(H - 2));
            const int   y0 = (int)y0f;
            const float wy = ysv - y0f;

            const float gxf = (float)gx / (float)(EXTENT - 1);
            const float xsv = (nx1 + (nx2 - nx1) * gxf) * (float)(W - 1);
            float x0f = floorf(xsv);
            x0f = fminf(fmaxf(x0f, 0.0f), (float)(W - 2));
            const int   x0 = (int)x0f;
            const float wx = xsv - x0f;

            base = feat + ((size_t)(y0 * W + x0)) * CHANNELS + c;
            w00 = (1.0f - wy) * (1.0f - wx);
            w01 = (1.0f - wy) * wx;
            w10 = wy * (1.0f - wx);
            w11 = wy * wx;
        };

        const float* base[3];
        float w00[3], w01[3], w10[3], w11[3];
        #pragma unroll
        for (int k = 0; k < 3; ++k)
            setup(sub + 16 * k, base[k], w00[k], w01[k], w10[k], w11[k]);

        // Issue ALL loads before any use (static indices -> registers).
        v4f f00[3], f01[3], f10[3], f11[3];
        #pragma unroll
        for (int k = 0; k < 3; ++k) {
            f00[k] = *(const v4f*)(base[k]);
            f01[k] = *(const v4f*)(base[k] + CHANNELS);
            f10[k] = *(const v4f*)(base[k] + rowstr);
            f11[k] = *(const v4f*)(base[k] + rowstr + CHANNELS);
        }

        // Tail point 48 (sub==0 only; wave-uniform branch).
        const bool tail = (sub == 0);
        const float* tb = base[0];
        float t00 = 0.f, t01 = 0.f, t10 = 0.f, t11 = 0.f;
        v4f g00 = {}, g01 = {}, g10 = {}, g11 = {};
        if (tail) {
            setup(48, tb, t00, t01, t10, t11);
            g00 = *(const v4f*)(tb);
            g01 = *(const v4f*)(tb + CHANNELS);
            g10 = *(const v4f*)(tb + rowstr);
            g11 = *(const v4f*)(tb + rowstr + CHANNELS);
        }

        // Blend + store (write-once data: nontemporal).
        #pragma unroll
        for (int k = 0; k < 3; ++k) {
            v4f r = f00[k] * w00[k] + f01[k] * w01[k]
                  + f10[k] * w10[k] + f11[k] * w11[k];
            __builtin_nontemporal_store(r, (v4f*)(outp + (size_t)(sub + 16 * k) * CHANNELS));
        }
        if (tail) {
            v4f r = g00 * t00 + g01 * t01 + g10 * t10 + g11 * t11;
            __builtin_nontemporal_store(r, (v4f*)(outp + (size_t)48 * CHANNELS));
        }
    }
}

extern "C" void kernel_launch(void* const* d_in, const int* in_sizes, int n_in,
                              void* d_out, int out_size, void* d_ws, size_t ws_size,
                              hipStream_t stream) {
    const float* metadata = (const float*)d_in[0];
    const float* boxes    = (const float*)d_in[1];
    const float* p2       = (const float*)d_in[2];
    const float* p3       = (const float*)d_in[3];
    const float* p4       = (const float*)d_in[4];
    const float* p5       = (const float*)d_in[5];
    float* out = (float*)d_out;
    int* sorted = (int*)d_ws;                 // n_boxes * 4 bytes

    const int n_boxes = in_sizes[1] / 4;      // 1024

    // Pass 1: bucket-sort box indices by (level, y-band). ~2-4 us.
    sort_boxes_kernel<<<dim3(1), dim3(1024), 0, stream>>>(
        metadata, boxes, sorted, n_boxes);

    // Pass 2: persistent sorted-window RoI align.
    const int nblocks = 512;
    roi_align_pyramid_kernel<<<dim3(nblocks), dim3(256), 0, stream>>>(
        metadata, boxes, p2, p3, p4, p5, sorted, out, n_boxes);
}